// Round 1
// baseline (80.817 us; speedup 1.0000x reference)
//
#include <hip/hip_runtime.h>

// ROI max pooling, replicating TF-style slicing/binning semantics:
//   half = floor(size/2); start = int(center-half); end = int(center+half)
//   len = end-start; step = max(len/7, 1)
//   bin k<6: rel coords [k*step,(k+1)*step); bin 6: [6*step, len)
// Dims fixed by the reference problem instance.
#define PH 7
#define PW 7
#define BB 2
#define NN 96
#define HH 64
#define WW 64
#define CC 128

__global__ __launch_bounds__(64) void roi_pool_kernel(
    const float* __restrict__ fm,    // [B,H,W,C]
    const float* __restrict__ rois,  // [B,N,4] = [xc,yc,w,h]
    float* __restrict__ out)         // [B,N,PH,PW,C]
{
    const int blk = blockIdx.x;          // roi*49 + ph*7 + pw
    const int pw  = blk % PW;
    const int t   = blk / PW;
    const int ph  = t % PH;
    const int roi = t / PH;              // b*N + n
    const int b   = roi / NN;

    const float4 r = ((const float4*)rois)[roi];
    const float xx = r.x, yy = r.y, ww = r.z, hh = r.w;
    const float half_w = floorf(ww * 0.5f);
    const float half_h = floorf(hh * 0.5f);
    const int sx = (int)(xx - half_w);
    const int ex = (int)(xx + half_w);
    const int sy = (int)(yy - half_h);
    const int ey = (int)(yy + half_h);
    const int lx = ex - sx;
    const int ly = ey - sy;
    const int stx = max(lx / PW, 1);
    const int sty = max(ly / PH, 1);

    int x0 = sx + pw * stx;
    int x1 = (pw == PW - 1) ? ex : (x0 + stx);
    int y0 = sy + ph * sty;
    int y1 = (ph == PH - 1) ? ey : (y0 + sty);
    // clamp to image (no-op for this data distribution; cheap safety)
    x0 = max(x0, 0); x1 = min(x1, WW);
    y0 = max(y0, 0); y1 = min(y1, HH);

    const int c2 = threadIdx.x;          // channel pair 0..63
    float2 m = make_float2(-INFINITY, -INFINITY);
    const float2* fm2 = (const float2*)fm + (size_t)b * HH * WW * (CC / 2);
    for (int y = y0; y < y1; ++y) {
        const float2* row = fm2 + (size_t)y * WW * (CC / 2);
        for (int x = x0; x < x1; ++x) {
            float2 v = row[x * (CC / 2) + c2];
            m.x = fmaxf(m.x, v.x);
            m.y = fmaxf(m.y, v.y);
        }
    }
    ((float2*)out)[(size_t)blk * (CC / 2) + c2] = m;
}

extern "C" void kernel_launch(void* const* d_in, const int* in_sizes, int n_in,
                              void* d_out, int out_size, void* d_ws, size_t ws_size,
                              hipStream_t stream) {
    const float* fm   = (const float*)d_in[0];
    const float* rois = (const float*)d_in[1];
    float* out = (float*)d_out;
    const int nblocks = BB * NN * PH * PW;   // 9408
    roi_pool_kernel<<<nblocks, 64, 0, stream>>>(fm, rois, out);
}

// Round 2
// 70.583 us; speedup vs baseline: 1.1450x; 1.1450x over previous
//
#include <hip/hip_runtime.h>

// ROI max pooling, TF-style slicing/binning semantics:
//   half = floor(size/2); start = int(center-half); end = int(center+half)
//   len = end-start; step = max(len/7, 1)
//   bin k<6: rel [k*step,(k+1)*step); bin 6: [6*step, len)
#define PH 7
#define PW 7
#define BB 2
#define NN 96
#define HH 64
#define WW 64
#define CC 128   // 32 float4s per pixel

__global__ __launch_bounds__(256) void roi_pool_kernel(
    const float* __restrict__ fm,    // [B,H,W,C]
    const float* __restrict__ rois,  // [B,N,4] = [xc,yc,w,h]
    float* __restrict__ out)         // [B,N,PH,PW,C]
{
    const int wid  = threadIdx.x >> 6;            // wave 0..3 within block
    const int lane = threadIdx.x & 63;
    const int bin  = blockIdx.x * 4 + wid;        // global bin id, 0..9407

    const int pw  = bin % PW;
    int t         = bin / PW;
    const int ph  = t % PH;
    const int roi = t / PH;                       // b*N + n
    const int b   = roi / NN;

    const float4 r = ((const float4*)rois)[roi];
    const float half_w = floorf(r.z * 0.5f);
    const float half_h = floorf(r.w * 0.5f);
    const int sx = (int)(r.x - half_w);
    const int ex = (int)(r.x + half_w);
    const int sy = (int)(r.y - half_h);
    const int ey = (int)(r.y + half_h);
    const int stx = max((ex - sx) / PW, 1);
    const int sty = max((ey - sy) / PH, 1);

    int x0 = sx + pw * stx;
    int x1 = (pw == PW - 1) ? ex : (x0 + stx);
    int y0 = sy + ph * sty;
    int y1 = (ph == PH - 1) ? ey : (y0 + sty);
    x0 = max(x0, 0); x1 = min(x1, WW);
    y0 = max(y0, 0); y1 = min(y1, HH);

    // lane -> (x offset 0/1, channel quad 0..31); wave covers 2 pixels/iter, 1 KB/load
    const int xo = lane >> 5;
    const int c4 = lane & 31;

    float4 m = make_float4(-INFINITY, -INFINITY, -INFINITY, -INFINITY);
    const float4* fmb = (const float4*)fm + (size_t)b * HH * WW * (CC / 4);
    for (int y = y0; y < y1; ++y) {
        const float4* row = fmb + (size_t)y * WW * (CC / 4);
        for (int x = x0; x < x1; x += 2) {
            // clamp duplicate pixel for odd widths: stays inside the bin, max-safe
            const int xx = min(x + xo, x1 - 1);
            const float4 v = row[xx * (CC / 4) + c4];
            m.x = fmaxf(m.x, v.x);
            m.y = fmaxf(m.y, v.y);
            m.z = fmaxf(m.z, v.z);
            m.w = fmaxf(m.w, v.w);
        }
    }

    // combine the two half-waves (even/odd pixel columns, same channels)
    m.x = fmaxf(m.x, __shfl_xor(m.x, 32));
    m.y = fmaxf(m.y, __shfl_xor(m.y, 32));
    m.z = fmaxf(m.z, __shfl_xor(m.z, 32));
    m.w = fmaxf(m.w, __shfl_xor(m.w, 32));

    if (lane < 32) {
        ((float4*)out)[(size_t)bin * (CC / 4) + c4] = m;
    }
}

extern "C" void kernel_launch(void* const* d_in, const int* in_sizes, int n_in,
                              void* d_out, int out_size, void* d_ws, size_t ws_size,
                              hipStream_t stream) {
    const float* fm   = (const float*)d_in[0];
    const float* rois = (const float*)d_in[1];
    float* out = (float*)d_out;
    const int nbins = BB * NN * PH * PW;          // 9408 bins, 4 per block
    roi_pool_kernel<<<nbins / 4, 256, 0, stream>>>(fm, rois, out);
}

// Round 3
// 62.737 us; speedup vs baseline: 1.2882x; 1.1251x over previous
//
#include <hip/hip_runtime.h>

// ROI max pooling, TF-style slicing/binning semantics:
//   half = floor(size/2); start = int(center-half); end = int(center+half)
//   len = end-start; step = max(len/7, 1)
//   bin k<6: rel [k*step,(k+1)*step); bin 6: [6*step, len)
#define PH 7
#define PW 7
#define BB 2
#define NN 96
#define HH 64
#define WW 64
#define CC 128   // 32 float4s per pixel

__global__ __launch_bounds__(256) void roi_pool_kernel(
    const float* __restrict__ fm,    // [B,H,W,C]
    const float* __restrict__ rois,  // [B,N,4] = [xc,yc,w,h]
    float* __restrict__ out)         // [B,N,PH,PW,C]
{
    const int wid  = threadIdx.x >> 6;            // wave 0..3 within block
    const int lane = threadIdx.x & 63;
    const int bin  = blockIdx.x * 4 + wid;        // global bin id, 0..9407

    const int pw  = bin % PW;
    int t         = bin / PW;
    const int ph  = t % PH;
    const int roi = t / PH;                       // b*N + n
    const int b   = roi / NN;

    const float4 r = ((const float4*)rois)[roi];
    const float half_w = floorf(r.z * 0.5f);
    const float half_h = floorf(r.w * 0.5f);
    const int sx = (int)(r.x - half_w);
    const int ex = (int)(r.x + half_w);
    const int sy = (int)(r.y - half_h);
    const int ey = (int)(r.y + half_h);
    const int stx = max((ex - sx) / PW, 1);
    const int sty = max((ey - sy) / PH, 1);

    int x0 = sx + pw * stx;
    int x1 = (pw == PW - 1) ? ex : (x0 + stx);
    int y0 = sy + ph * sty;
    int y1 = (ph == PH - 1) ? ey : (y0 + sty);
    x0 = max(x0, 0); x1 = min(x1, WW);
    y0 = max(y0, 0); y1 = min(y1, HH);

    // lane -> (x offset 0/1, channel quad 0..31); wave covers 2 pixels/slot, 1 KB/load
    const int xo = lane >> 5;
    const int c4 = lane & 31;

    // Flatten window to P = ny*nx slots; slot p -> row p/nx, x-pair p%nx.
    // nx <= 5, ny <= 10 for this data (len in [16,40], step in [2,5], tail <= 10).
    const int nx = (x1 - x0 + 1) >> 1;            // ceil((x1-x0)/2), pairs per row
    const int ny = y1 - y0;
    const int P  = max(nx * ny, 1);
    // exact reciprocal for /nx: valid for p*nx < 65536 (here p <= 50, nx <= 5)
    const unsigned rcp = (65536u + (unsigned)nx - 1u) / (unsigned)nx;

    float4 m = make_float4(-INFINITY, -INFINITY, -INFINITY, -INFINITY);
    const float4* fmb = (const float4*)fm + (size_t)b * HH * WW * (CC / 4);

#pragma unroll 4
    for (int p = 0; p < P; ++p) {
        const int yy = (int)(((unsigned)p * rcp) >> 16);   // p / nx
        const int rem = p - yy * nx;                       // p % nx
        const int xx = min(x0 + 2 * rem + xo, x1 - 1);     // clamp dup: max-safe
        const float4 v = fmb[(size_t)(y0 + yy) * WW * (CC / 4) + xx * (CC / 4) + c4];
        m.x = fmaxf(m.x, v.x);
        m.y = fmaxf(m.y, v.y);
        m.z = fmaxf(m.z, v.z);
        m.w = fmaxf(m.w, v.w);
    }

    // combine the two half-waves (even/odd pixel columns, same channels)
    m.x = fmaxf(m.x, __shfl_xor(m.x, 32));
    m.y = fmaxf(m.y, __shfl_xor(m.y, 32));
    m.z = fmaxf(m.z, __shfl_xor(m.z, 32));
    m.w = fmaxf(m.w, __shfl_xor(m.w, 32));

    if (lane < 32) {
        ((float4*)out)[(size_t)bin * (CC / 4) + c4] = m;
    }
}

extern "C" void kernel_launch(void* const* d_in, const int* in_sizes, int n_in,
                              void* d_out, int out_size, void* d_ws, size_t ws_size,
                              hipStream_t stream) {
    const float* fm   = (const float*)d_in[0];
    const float* rois = (const float*)d_in[1];
    float* out = (float*)d_out;
    const int nbins = BB * NN * PH * PW;          // 9408 bins, 4 per block
    roi_pool_kernel<<<nbins / 4, 256, 0, stream>>>(fm, rois, out);
}